// Round 7
// baseline (99.103 us; speedup 1.0000x reference)
//
#include <hip/hip_runtime.h>
#include <hip/hip_bf16.h>

// ROI Align fp32, NCHW input (B=2, C=256, H=W=200), pooled 7x7, SAMPLE_NUM=2,
// SPATIAL_SCALE=0.25, ROI_END_MODE=1.
//
// Round 7: per-cell corner dedup. The 2x2-sample x 2x2-corner sum factorizes:
//   out[cell] = sum_r sum_c Wy(r) * Wx(c) * V[r][c]
// with Wy/Wx merging duplicate corner rows/cols (weights add) and zero-weight
// entries skipped (fy==0, clamped-hi, invalid samples). Cuts pixel loads per
// cell from 16 to ~10-12 (~30% fewer gathered bytes at the ~10 TB/s wall).
// Geometry is wave-uniform -> all skip branches are coherent.
// Pipeline (unchanged otherwise):
//   Phase 0: roi_bin_kernel -> perm[] (1 small block)
//   Phase 1: NCHW fp32 -> NHWC bf16 transpose into d_ws (41 MB)
//   Phase 2: gather (512 thr / ROI), chunked XCD mapping via perm

constexpr int C_TOT  = 256;
constexpr int H_FEAT = 200;
constexpr int W_FEAT = 200;
constexpr int HW     = H_FEAT * W_FEAT;
constexpr int S_TOT  = 49;             // 7*7 pooled cells
constexpr size_t FEATT_BYTES = (size_t)2 * HW * C_TOT * sizeof(unsigned short); // 40.96 MB
constexpr int NXCD = 8;
constexpr int NBUCKET = 32;            // b(1) x qy(2) x qx(2) bits

// ---------------------------------------------------------------- ROI binning
__global__ __launch_bounds__(1024) void roi_bin_kernel(
    const float* __restrict__ rois, int* __restrict__ perm, int N)
{
    __shared__ int hist[NBUCKET];
    __shared__ int base[NBUCKET];
    __shared__ int cnt[NBUCKET];
    int t = threadIdx.x;

    if (t < NBUCKET) { hist[t] = 0; cnt[t] = 0; }
    __syncthreads();

    int bucket = -1;
    if (t < N) {
        const float* r = rois + (size_t)t * 5;
        int   b  = (int)r[0];
        float cx = (r[1] + r[3]) * 0.5f * 0.25f;   // feature-space center
        float cy = (r[2] + r[4]) * 0.5f * 0.25f;
        int qx = min(max((int)(cx * (4.0f / 200.0f)), 0), 3);
        int qy = min(max((int)(cy * (4.0f / 200.0f)), 0), 3);
        bucket = ((b & 1) << 4) | (qy << 2) | qx;
        atomicAdd(&hist[bucket], 1);
    }
    __syncthreads();

    if (t == 0) {
        int acc = 0;
        for (int i = 0; i < NBUCKET; ++i) { base[i] = acc; acc += hist[i]; }
    }
    __syncthreads();

    if (t < N) {
        int pos = base[bucket] + atomicAdd(&cnt[bucket], 1);
        perm[pos] = t;
    }
}

// ---------------------------------------------------------------- transpose
// feat[b][c][s] (fp32) -> featT[b][s][c] (bf16, RNE).
__global__ __launch_bounds__(256) void nchw_to_nhwc_bf16_kernel(
    const float* __restrict__ feat,
    unsigned short* __restrict__ featT)
{
    __shared__ float tile[32][33];
    int tx = threadIdx.x;        // 0..31
    int ty = threadIdx.y;        // 0..7
    int s0 = blockIdx.x * 32;
    int c0 = blockIdx.y * 32;
    int b  = blockIdx.z;

    const float* src = feat + ((size_t)b * C_TOT) * HW;
    #pragma unroll
    for (int i = 0; i < 4; ++i) {
        int r = ty + i * 8;      // channel within tile
        tile[r][tx] = src[(size_t)(c0 + r) * HW + (s0 + tx)];
    }
    __syncthreads();
    unsigned short* dst = featT + ((size_t)b * HW) * C_TOT;
    #pragma unroll
    for (int i = 0; i < 4; ++i) {
        int r = ty + i * 8;      // spatial within tile
        float x = tile[tx][r];
        unsigned int u = __float_as_uint(x);
        unsigned int rb = (u + 0x7fffu + ((u >> 16) & 1u)) >> 16;   // RNE
        dst[(size_t)(s0 + r) * C_TOT + (c0 + tx)] = (unsigned short)rb;
    }
}

// Build merged (index, weight) candidate list for one axis of one cell.
// cand rows: lo0, hi0, lo1, hi1 (clamped); duplicate indices merge weights.
__device__ __forceinline__ void axis_candidates(
    float start, float bin, int p, int size, int idx[4], float w[4])
{
    #pragma unroll
    for (int i = 0; i < 2; ++i) {
        float g  = (float)(2 * p + i);
        float c  = start + bin * ((g + 0.5f) * 0.5f);
        bool  v  = (c >= -1.0f) && (c <= (float)size);
        float cc = fminf(fmaxf(c, 0.0f), (float)(size - 1));
        int   lo = (int)cc;
        int   hi = min(lo + 1, size - 1);
        float f  = cc - (float)lo;
        idx[2 * i + 0] = lo;
        idx[2 * i + 1] = hi;
        // fold 0.5 per axis -> product carries the 0.25 sample-average
        w[2 * i + 0] = v ? (1.0f - f) * 0.5f : 0.0f;
        w[2 * i + 1] = v ? f * 0.5f          : 0.0f;
    }
    // merge duplicates (fully unrolled, static indexing)
    #pragma unroll
    for (int k = 1; k < 4; ++k) {
        #pragma unroll
        for (int m = 0; m < k; ++m) {
            if (idx[k] == idx[m]) {
                w[m] += w[k];
                w[k] = 0.0f;
                idx[k] = -1;
                break;
            }
        }
    }
}

// ---------------------------------------------------------------- gather
__global__ __launch_bounds__(512) void roi_align_nhwc_kernel(
    const unsigned short* __restrict__ featT,
    const float* __restrict__ rois,
    const int* __restrict__ perm,
    float* __restrict__ out,
    int N, int use_perm)
{
    __shared__ alignas(16) float tile[C_TOT * S_TOT];   // [c][s] == output order

    int n;
    if (use_perm) {
        // chunked XCD transform: XCD x gets sorted ranks [x*chunk, (x+1)*chunk)
        int chunk = (N + NXCD - 1) / NXCD;
        int rank  = (blockIdx.x & (NXCD - 1)) * chunk + (blockIdx.x >> 3);
        if (rank >= N) rank = blockIdx.x;
        n = perm[rank];
    } else {
        n = blockIdx.x;
    }

    int tid  = threadIdx.x;
    int wave = tid >> 6;         // 0..7
    int lane = tid & 63;

    const float* r = rois + (size_t)n * 5;
    int   b  = (int)r[0];
    float x1 = r[1] * 0.25f;
    float y1 = r[2] * 0.25f;
    float x2 = (r[3] + 1.0f) * 0.25f;
    float y2 = (r[4] + 1.0f) * 0.25f;
    float bin_w = fmaxf(x2 - x1, 1.0f) * (1.0f / 7.0f);
    float bin_h = fmaxf(y2 - y1, 1.0f) * (1.0f / 7.0f);

    const unsigned short* fbase =
        featT + (size_t)b * HW * C_TOT + (size_t)lane * 4;

    for (int s = wave; s < S_TOT; s += 8) {
        int ph = s / 7;
        int pw = s - ph * 7;

        int   ry[4]; float wy[4];
        int   cx[4]; float wx[4];
        axis_candidates(y1, bin_h, ph, H_FEAT, ry, wy);
        axis_candidates(x1, bin_w, pw, W_FEAT, cx, wx);

        float4 acc = make_float4(0.f, 0.f, 0.f, 0.f);
        #pragma unroll
        for (int a = 0; a < 4; ++a) {
            if (wy[a] != 0.0f) {                     // wave-uniform branch
                int rowoff = ry[a] * W_FEAT;
                #pragma unroll
                for (int e = 0; e < 4; ++e) {
                    if (wx[e] != 0.0f) {             // wave-uniform branch
                        float w = wy[a] * wx[e];
                        const ushort4 v = *reinterpret_cast<const ushort4*>(
                            fbase + (size_t)(rowoff + cx[e]) * C_TOT);
                        float f0 = __uint_as_float((unsigned int)v.x << 16);
                        float f1 = __uint_as_float((unsigned int)v.y << 16);
                        float f2 = __uint_as_float((unsigned int)v.z << 16);
                        float f3 = __uint_as_float((unsigned int)v.w << 16);
                        acc.x = fmaf(w, f0, acc.x);
                        acc.y = fmaf(w, f1, acc.y);
                        acc.z = fmaf(w, f2, acc.z);
                        acc.w = fmaf(w, f3, acc.w);
                    }
                }
            }
        }

        int c = lane * 4;
        tile[(c + 0) * S_TOT + s] = acc.x;
        tile[(c + 1) * S_TOT + s] = acc.y;
        tile[(c + 2) * S_TOT + s] = acc.z;
        tile[(c + 3) * S_TOT + s] = acc.w;
    }
    __syncthreads();

    // Linear float4 store: tile flat layout == out[n] flat layout.
    const float4* t4 = reinterpret_cast<const float4*>(tile);
    float4* o4 = reinterpret_cast<float4*>(out + (size_t)n * (C_TOT * S_TOT));
    constexpr int Q = C_TOT * S_TOT / 4;   // 3136
    for (int q = tid; q < Q; q += 512)
        o4[q] = t4[q];
}

// ---------------------------------------------------------------- fp32 fallback
constexpr int CPT = 4;
constexpr int CG  = C_TOT / CPT;

__global__ __launch_bounds__(256) void roi_align_direct_kernel(
    const float* __restrict__ feat,
    const float* __restrict__ rois,
    float* __restrict__ out,
    int N)
{
    int t = blockIdx.x * 256 + threadIdx.x;
    int total = N * CG * S_TOT;
    if (t >= total) return;

    int s   = t % S_TOT;
    int rem = t / S_TOT;
    int c0  = rem % CG;
    int n   = rem / CG;
    int ph  = s / 7;
    int pw  = s - ph * 7;

    const float* r = rois + (size_t)n * 5;
    int   b  = (int)r[0];
    float x1 = r[1] * 0.25f;
    float y1 = r[2] * 0.25f;
    float x2 = (r[3] + 1.0f) * 0.25f;
    float y2 = (r[4] + 1.0f) * 0.25f;
    float bin_w = fmaxf(x2 - x1, 1.0f) * (1.0f / 7.0f);
    float bin_h = fmaxf(y2 - y1, 1.0f) * (1.0f / 7.0f);

    int   roff[2][2], coff[2][2];
    float wy[2][2], wx[2][2];
    #pragma unroll
    for (int i = 0; i < 2; ++i) {
        float gy  = (float)(2 * ph + i);
        float cy  = y1 + bin_h * ((gy + 0.5f) * 0.5f);
        bool  vy  = (cy >= -1.0f) && (cy <= (float)H_FEAT);
        float ccy = fminf(fmaxf(cy, 0.0f), (float)(H_FEAT - 1));
        int   ylo = (int)ccy;
        int   yhi = min(ylo + 1, H_FEAT - 1);
        float fy  = ccy - (float)ylo;
        roff[i][0] = ylo * W_FEAT;
        roff[i][1] = yhi * W_FEAT;
        wy[i][0] = vy ? (1.0f - fy) : 0.0f;
        wy[i][1] = vy ? fy          : 0.0f;

        float gx  = (float)(2 * pw + i);
        float cx  = x1 + bin_w * ((gx + 0.5f) * 0.5f);
        bool  vx  = (cx >= -1.0f) && (cx <= (float)W_FEAT);
        float ccx = fminf(fmaxf(cx, 0.0f), (float)(W_FEAT - 1));
        int   xlo = (int)ccx;
        int   xhi = min(xlo + 1, W_FEAT - 1);
        float fx  = ccx - (float)xlo;
        coff[i][0] = xlo;
        coff[i][1] = xhi;
        wx[i][0] = vx ? (1.0f - fx) : 0.0f;
        wx[i][1] = vx ? fx          : 0.0f;
    }

    float w16[16];
    int   o16[16];
    #pragma unroll
    for (int iy = 0; iy < 2; ++iy)
    #pragma unroll
    for (int ix = 0; ix < 2; ++ix)
    #pragma unroll
    for (int jy = 0; jy < 2; ++jy)
    #pragma unroll
    for (int jx = 0; jx < 2; ++jx) {
        int idx = ((iy * 2 + ix) * 2 + jy) * 2 + jx;
        w16[idx] = wy[iy][jy] * wx[ix][jx];
        o16[idx] = roff[iy][jy] + coff[ix][jx];
    }

    size_t base  = ((size_t)b * C_TOT + c0) * HW;
    size_t obase = (size_t)n * (C_TOT * S_TOT) + (size_t)c0 * S_TOT + s;

    #pragma unroll
    for (int k = 0; k < CPT; ++k) {
        const float* f = feat + base + (size_t)k * CG * HW;
        float acc = 0.0f;
        #pragma unroll
        for (int j = 0; j < 16; ++j)
            acc = fmaf(w16[j], f[o16[j]], acc);
        out[obase + (size_t)k * (CG * S_TOT)] = acc * 0.25f;
    }
}

extern "C" void kernel_launch(void* const* d_in, const int* in_sizes, int n_in,
                              void* d_out, int out_size, void* d_ws, size_t ws_size,
                              hipStream_t stream) {
    const float* feat = (const float*)d_in[0];
    const float* rois = (const float*)d_in[1];
    float* out = (float*)d_out;
    int N = in_sizes[1] / 5;

    size_t need = FEATT_BYTES + 4096;
    if (ws_size >= need) {
        unsigned short* featT = (unsigned short*)d_ws;
        int* perm = (int*)((char*)d_ws + FEATT_BYTES);
        int use_perm = (N <= 1024) ? 1 : 0;
        if (use_perm)
            roi_bin_kernel<<<1, 1024, 0, stream>>>(rois, perm, N);
        dim3 tgrid(HW / 32, C_TOT / 32, 2);
        dim3 tblk(32, 8);
        nchw_to_nhwc_bf16_kernel<<<tgrid, tblk, 0, stream>>>(feat, featT);
        roi_align_nhwc_kernel<<<N, 512, 0, stream>>>(featT, rois, perm, out, N, use_perm);
    } else {
        int total  = N * CG * S_TOT;
        int blocks = (total + 255) / 256;
        roi_align_direct_kernel<<<blocks, 256, 0, stream>>>(feat, rois, out, N);
    }
}

// Round 8
// 60.799 us; speedup vs baseline: 1.6300x; 1.6300x over previous
//
#include <hip/hip_runtime.h>
#include <hip/hip_bf16.h>

// ROI Align fp32, NCHW input (B=2, C=256, H=W=200), pooled 7x7, SAMPLE_NUM=2,
// SPATIAL_SCALE=0.25, ROI_END_MODE=1.
//
// Round 8: revert round-7's branchy dedup (it serialized the gather: 39->76us).
// Back to unconditional 16-corner body, but pack TWO corner pixels per
// dwordx4 wave-load: lanes 0-31 read pixel A (512 B), lanes 32-63 pixel B
// (xlo/xhi pair -> usually 1 KB contiguous). Halves gather instructions at
// identical bytes -> distinguishes per-request vs per-byte service wall.
// Each lane holds 8 channels; one __shfl_xor(32) per acc merges the halves.
// LDS writes use an XOR bank swizzle (verified conflict-free); copy-out
// inverts it with contiguous float4 stores.
//   Phase 0: roi_bin_kernel -> perm[] (1 small block, ~1us)
//   Phase 1: NCHW fp32 -> NHWC bf16 transpose into d_ws (41 MB, ~20us, at HBM ceiling)
//   Phase 2: gather (512 thr / ROI), chunked XCD mapping via perm

constexpr int C_TOT  = 256;
constexpr int H_FEAT = 200;
constexpr int W_FEAT = 200;
constexpr int HW     = H_FEAT * W_FEAT;
constexpr int S_TOT  = 49;             // 7*7 pooled cells
constexpr size_t FEATT_BYTES = (size_t)2 * HW * C_TOT * sizeof(unsigned short); // 40.96 MB
constexpr int NXCD = 8;
constexpr int NBUCKET = 32;            // b(1) x qy(2) x qx(2) bits

// ---------------------------------------------------------------- ROI binning
__global__ __launch_bounds__(1024) void roi_bin_kernel(
    const float* __restrict__ rois, int* __restrict__ perm, int N)
{
    __shared__ int hist[NBUCKET];
    __shared__ int base[NBUCKET];
    __shared__ int cnt[NBUCKET];
    int t = threadIdx.x;

    if (t < NBUCKET) { hist[t] = 0; cnt[t] = 0; }
    __syncthreads();

    int bucket = -1;
    if (t < N) {
        const float* r = rois + (size_t)t * 5;
        int   b  = (int)r[0];
        float cx = (r[1] + r[3]) * 0.5f * 0.25f;   // feature-space center
        float cy = (r[2] + r[4]) * 0.5f * 0.25f;
        int qx = min(max((int)(cx * (4.0f / 200.0f)), 0), 3);
        int qy = min(max((int)(cy * (4.0f / 200.0f)), 0), 3);
        bucket = ((b & 1) << 4) | (qy << 2) | qx;
        atomicAdd(&hist[bucket], 1);
    }
    __syncthreads();

    if (t == 0) {
        int acc = 0;
        for (int i = 0; i < NBUCKET; ++i) { base[i] = acc; acc += hist[i]; }
    }
    __syncthreads();

    if (t < N) {
        int pos = base[bucket] + atomicAdd(&cnt[bucket], 1);
        perm[pos] = t;
    }
}

// ---------------------------------------------------------------- transpose
// feat[b][c][s] (fp32) -> featT[b][s][c] (bf16, RNE).
__global__ __launch_bounds__(256) void nchw_to_nhwc_bf16_kernel(
    const float* __restrict__ feat,
    unsigned short* __restrict__ featT)
{
    __shared__ float tile[32][33];
    int tx = threadIdx.x;        // 0..31
    int ty = threadIdx.y;        // 0..7
    int s0 = blockIdx.x * 32;
    int c0 = blockIdx.y * 32;
    int b  = blockIdx.z;

    const float* src = feat + ((size_t)b * C_TOT) * HW;
    #pragma unroll
    for (int i = 0; i < 4; ++i) {
        int r = ty + i * 8;      // channel within tile
        tile[r][tx] = src[(size_t)(c0 + r) * HW + (s0 + tx)];
    }
    __syncthreads();
    unsigned short* dst = featT + ((size_t)b * HW) * C_TOT;
    #pragma unroll
    for (int i = 0; i < 4; ++i) {
        int r = ty + i * 8;      // spatial within tile
        float x = tile[tx][r];
        unsigned int u = __float_as_uint(x);
        unsigned int rb = (u + 0x7fffu + ((u >> 16) & 1u)) >> 16;   // RNE
        dst[(size_t)(s0 + r) * C_TOT + (c0 + tx)] = (unsigned short)rb;
    }
}

// ---------------------------------------------------------------- gather
__global__ __launch_bounds__(512) void roi_align_nhwc_kernel(
    const unsigned short* __restrict__ featT,
    const float* __restrict__ rois,
    const int* __restrict__ perm,
    float* __restrict__ out,
    int N, int use_perm)
{
    // tile[slot_ch][s]; slot_ch = (ch & ~7) | ((ch&7) ^ ((ch>>5)&7))
    __shared__ alignas(16) float tile[C_TOT * S_TOT];

    int n;
    if (use_perm) {
        // chunked XCD transform: XCD x gets sorted ranks [x*chunk, (x+1)*chunk)
        int chunk = (N + NXCD - 1) / NXCD;
        int rank  = (blockIdx.x & (NXCD - 1)) * chunk + (blockIdx.x >> 3);
        if (rank >= N) rank = blockIdx.x;
        n = perm[rank];
    } else {
        n = blockIdx.x;
    }

    int tid  = threadIdx.x;
    int wave = tid >> 6;         // 0..7
    int lane = tid & 63;
    int half = lane >> 5;        // 0: pixel A (even corner), 1: pixel B (odd)
    int li   = lane & 31;        // channel-group within half: ch 8*li..8*li+7

    const float* r = rois + (size_t)n * 5;
    int   b  = (int)r[0];
    float x1 = r[1] * 0.25f;
    float y1 = r[2] * 0.25f;
    float x2 = (r[3] + 1.0f) * 0.25f;
    float y2 = (r[4] + 1.0f) * 0.25f;
    float bin_w = fmaxf(x2 - x1, 1.0f) * (1.0f / 7.0f);
    float bin_h = fmaxf(y2 - y1, 1.0f) * (1.0f / 7.0f);

    const unsigned short* fb = featT + (size_t)b * HW * C_TOT + li * 8;
    int xorsw = (li >> 2) & 7;

    for (int s = wave; s < S_TOT; s += 8) {
        int ph = s / 7;
        int pw = s - ph * 7;

        int   yoff[2][2];
        int   xoff[2][2];
        float wy[2][2], wx[2][2];
        #pragma unroll
        for (int i = 0; i < 2; ++i) {
            float gy  = (float)(2 * ph + i);
            float cy  = y1 + bin_h * ((gy + 0.5f) * 0.5f);
            bool  vy  = (cy >= -1.0f) && (cy <= (float)H_FEAT);
            float ccy = fminf(fmaxf(cy, 0.0f), (float)(H_FEAT - 1));
            int   ylo = (int)ccy;
            int   yhi = min(ylo + 1, H_FEAT - 1);
            float fy  = ccy - (float)ylo;
            yoff[i][0] = ylo * W_FEAT;
            yoff[i][1] = yhi * W_FEAT;
            // fold 0.5 per axis -> product carries the 0.25 sample-average
            wy[i][0] = vy ? (1.0f - fy) * 0.5f : 0.0f;
            wy[i][1] = vy ? fy * 0.5f          : 0.0f;

            float gx  = (float)(2 * pw + i);
            float cx  = x1 + bin_w * ((gx + 0.5f) * 0.5f);
            bool  vx  = (cx >= -1.0f) && (cx <= (float)W_FEAT);
            float ccx = fminf(fmaxf(cx, 0.0f), (float)(W_FEAT - 1));
            int   xlo = (int)ccx;
            int   xhi = min(xlo + 1, W_FEAT - 1);
            float fx  = ccx - (float)xlo;
            xoff[i][0] = xlo;
            xoff[i][1] = xhi;
            wx[i][0] = vx ? (1.0f - fx) * 0.5f : 0.0f;
            wx[i][1] = vx ? fx * 0.5f          : 0.0f;
        }

        float acc[8];
        #pragma unroll
        for (int j = 0; j < 8; ++j) acc[j] = 0.0f;

        // 8 paired wave-loads: half 0 reads the xlo corner, half 1 the xhi.
        #pragma unroll
        for (int iy = 0; iy < 2; ++iy)
        #pragma unroll
        for (int jy = 0; jy < 2; ++jy)
        #pragma unroll
        for (int ix = 0; ix < 2; ++ix) {
            int   pixA = yoff[iy][jy] + xoff[ix][0];
            int   pixB = yoff[iy][jy] + xoff[ix][1];
            float wA   = wy[iy][jy] * wx[ix][0];
            float wB   = wy[iy][jy] * wx[ix][1];
            int   pix  = half ? pixB : pixA;
            float w    = half ? wB   : wA;
            const uint4 v = *reinterpret_cast<const uint4*>(
                fb + (size_t)pix * C_TOT);
            unsigned int u;
            u = v.x;
            acc[0] = fmaf(w, __uint_as_float(u << 16),          acc[0]);
            acc[1] = fmaf(w, __uint_as_float(u & 0xffff0000u),  acc[1]);
            u = v.y;
            acc[2] = fmaf(w, __uint_as_float(u << 16),          acc[2]);
            acc[3] = fmaf(w, __uint_as_float(u & 0xffff0000u),  acc[3]);
            u = v.z;
            acc[4] = fmaf(w, __uint_as_float(u << 16),          acc[4]);
            acc[5] = fmaf(w, __uint_as_float(u & 0xffff0000u),  acc[5]);
            u = v.w;
            acc[6] = fmaf(w, __uint_as_float(u << 16),          acc[6]);
            acc[7] = fmaf(w, __uint_as_float(u & 0xffff0000u),  acc[7]);
        }

        // merge the two corner-halves; lanes 0-31 hold the full sum for
        // channels 8*li .. 8*li+7 and write LDS with a conflict-free swizzle.
        #pragma unroll
        for (int j = 0; j < 8; ++j) {
            float sum = acc[j] + __shfl_xor(acc[j], 32);
            if (half == 0) {
                int slot_ch = li * 8 + (j ^ xorsw);
                tile[slot_ch * S_TOT + s] = sum;
            }
        }
    }
    __syncthreads();

    // Copy-out: invert the channel swizzle, contiguous float4 global stores.
    float4* o4 = reinterpret_cast<float4*>(out + (size_t)n * (C_TOT * S_TOT));
    constexpr int Q4 = C_TOT * S_TOT / 4;   // 3136
    for (int q4 = tid; q4 < Q4; q4 += 512) {
        int q = q4 * 4;
        float4 val;
        float* vp = reinterpret_cast<float*>(&val);
        #pragma unroll
        for (int e = 0; e < 4; ++e) {
            int qq = q + e;
            int ch = qq / S_TOT;
            int ss = qq - ch * S_TOT;
            int slot_ch = (ch & ~7) | ((ch & 7) ^ ((ch >> 5) & 7));
            vp[e] = tile[slot_ch * S_TOT + ss];
        }
        o4[q4] = val;
    }
}

// ---------------------------------------------------------------- fp32 fallback
constexpr int CPT = 4;
constexpr int CG  = C_TOT / CPT;

__global__ __launch_bounds__(256) void roi_align_direct_kernel(
    const float* __restrict__ feat,
    const float* __restrict__ rois,
    float* __restrict__ out,
    int N)
{
    int t = blockIdx.x * 256 + threadIdx.x;
    int total = N * CG * S_TOT;
    if (t >= total) return;

    int s   = t % S_TOT;
    int rem = t / S_TOT;
    int c0  = rem % CG;
    int n   = rem / CG;
    int ph  = s / 7;
    int pw  = s - ph * 7;

    const float* r = rois + (size_t)n * 5;
    int   b  = (int)r[0];
    float x1 = r[1] * 0.25f;
    float y1 = r[2] * 0.25f;
    float x2 = (r[3] + 1.0f) * 0.25f;
    float y2 = (r[4] + 1.0f) * 0.25f;
    float bin_w = fmaxf(x2 - x1, 1.0f) * (1.0f / 7.0f);
    float bin_h = fmaxf(y2 - y1, 1.0f) * (1.0f / 7.0f);

    int   roff[2][2], coff[2][2];
    float wy[2][2], wx[2][2];
    #pragma unroll
    for (int i = 0; i < 2; ++i) {
        float gy  = (float)(2 * ph + i);
        float cy  = y1 + bin_h * ((gy + 0.5f) * 0.5f);
        bool  vy  = (cy >= -1.0f) && (cy <= (float)H_FEAT);
        float ccy = fminf(fmaxf(cy, 0.0f), (float)(H_FEAT - 1));
        int   ylo = (int)ccy;
        int   yhi = min(ylo + 1, H_FEAT - 1);
        float fy  = ccy - (float)ylo;
        roff[i][0] = ylo * W_FEAT;
        roff[i][1] = yhi * W_FEAT;
        wy[i][0] = vy ? (1.0f - fy) : 0.0f;
        wy[i][1] = vy ? fy          : 0.0f;

        float gx  = (float)(2 * pw + i);
        float cx  = x1 + bin_w * ((gx + 0.5f) * 0.5f);
        bool  vx  = (cx >= -1.0f) && (cx <= (float)W_FEAT);
        float ccx = fminf(fmaxf(cx, 0.0f), (float)(W_FEAT - 1));
        int   xlo = (int)ccx;
        int   xhi = min(xlo + 1, W_FEAT - 1);
        float fx  = ccx - (float)xlo;
        coff[i][0] = xlo;
        coff[i][1] = xhi;
        wx[i][0] = vx ? (1.0f - fx) : 0.0f;
        wx[i][1] = vx ? fx          : 0.0f;
    }

    float w16[16];
    int   o16[16];
    #pragma unroll
    for (int iy = 0; iy < 2; ++iy)
    #pragma unroll
    for (int ix = 0; ix < 2; ++ix)
    #pragma unroll
    for (int jy = 0; jy < 2; ++jy)
    #pragma unroll
    for (int jx = 0; jx < 2; ++jx) {
        int idx = ((iy * 2 + ix) * 2 + jy) * 2 + jx;
        w16[idx] = wy[iy][jy] * wx[ix][jx];
        o16[idx] = roff[iy][jy] + coff[ix][jx];
    }

    size_t base  = ((size_t)b * C_TOT + c0) * HW;
    size_t obase = (size_t)n * (C_TOT * S_TOT) + (size_t)c0 * S_TOT + s;

    #pragma unroll
    for (int k = 0; k < CPT; ++k) {
        const float* f = feat + base + (size_t)k * CG * HW;
        float acc = 0.0f;
        #pragma unroll
        for (int j = 0; j < 16; ++j)
            acc = fmaf(w16[j], f[o16[j]], acc);
        out[obase + (size_t)k * (CG * S_TOT)] = acc * 0.25f;
    }
}

extern "C" void kernel_launch(void* const* d_in, const int* in_sizes, int n_in,
                              void* d_out, int out_size, void* d_ws, size_t ws_size,
                              hipStream_t stream) {
    const float* feat = (const float*)d_in[0];
    const float* rois = (const float*)d_in[1];
    float* out = (float*)d_out;
    int N = in_sizes[1] / 5;

    size_t need = FEATT_BYTES + 4096;
    if (ws_size >= need) {
        unsigned short* featT = (unsigned short*)d_ws;
        int* perm = (int*)((char*)d_ws + FEATT_BYTES);
        int use_perm = (N <= 1024) ? 1 : 0;
        if (use_perm)
            roi_bin_kernel<<<1, 1024, 0, stream>>>(rois, perm, N);
        dim3 tgrid(HW / 32, C_TOT / 32, 2);
        dim3 tblk(32, 8);
        nchw_to_nhwc_bf16_kernel<<<tgrid, tblk, 0, stream>>>(feat, featT);
        roi_align_nhwc_kernel<<<N, 512, 0, stream>>>(featT, rois, perm, out, N, use_perm);
    } else {
        int total  = N * CG * S_TOT;
        int blocks = (total + 255) / 256;
        roi_align_direct_kernel<<<blocks, 256, 0, stream>>>(feat, rois, out, N);
    }
}